// Round 1
// baseline (34.023 us; speedup 1.0000x reference)
//
#include <hip/hip_runtime.h>
#include <hip/hip_bf16.h>

#define MM 16      // mixtures
#define DD 128     // visible dims
#define CC 50      // categories
#define BB 32768   // batch

// ---------------------------------------------------------------------------
// Kernel 1: compute logw[M] and logp transposed to [D][C][M] layout so the
// 16 m-values for a given (d, c) are contiguous (64B, coalesced gather).
// ---------------------------------------------------------------------------
__global__ __launch_bounds__(256) void prep_kernel(
    const float* __restrict__ cate,   // [M][D][C]
    const float* __restrict__ mw,     // [M]
    float* __restrict__ logp_t,       // [D][C][M]
    float* __restrict__ logw)         // [M]
{
    int gid = blockIdx.x * blockDim.x + threadIdx.x;
    if (gid < MM * DD) {
        int m = gid >> 7;       // gid / DD
        int d = gid & (DD - 1); // gid % DD
        const float* row = cate + (m * DD + d) * CC;
        float v[CC];
        float mx = -1e30f;
        #pragma unroll
        for (int c = 0; c < CC; ++c) { v[c] = row[c]; mx = fmaxf(mx, v[c]); }
        float s = 0.f;
        #pragma unroll
        for (int c = 0; c < CC; ++c) s += __expf(v[c] - mx);
        float lse = mx + __logf(s);
        #pragma unroll
        for (int c = 0; c < CC; ++c)
            logp_t[(d * CC + c) * MM + m] = v[c] - lse;
    }
    if (gid < MM) {
        float mx = -1e30f;
        #pragma unroll
        for (int i = 0; i < MM; ++i) mx = fmaxf(mx, mw[i]);
        float s = 0.f;
        #pragma unroll
        for (int i = 0; i < MM; ++i) s += __expf(mw[i] - mx);
        logw[gid] = mw[gid] - (mx + __logf(s));
    }
}

// ---------------------------------------------------------------------------
// Kernel 2: each group of 16 lanes handles one batch row b; lane l within the
// group owns mixture m = l. Per d: c = x[b,d]; the 16 lanes read the 16
// contiguous floats logp_t[d][c][0..15] (one coalesced 64B segment).
// Then logsumexp over the 16-lane group via shfl_xor.
// Block = 256 threads = 16 rows; grid = B/16 = 2048 blocks -> 32 waves/CU.
// ---------------------------------------------------------------------------
__global__ __launch_bounds__(256) void gather_kernel(
    const int* __restrict__ x,        // [B][D] int32
    const float* __restrict__ logp_t, // [D][C][M]
    const float* __restrict__ logw,   // [M]
    float* __restrict__ out)          // [B]
{
    const int tid  = threadIdx.x;
    const int m    = tid & 15;
    const int bsub = tid >> 4;                 // 0..15
    const int b    = blockIdx.x * 16 + bsub;

    const int4* __restrict__ xrow = (const int4*)(x + b * DD);
    const float* __restrict__ tab = logp_t + m;

    float acc = 0.f;
    #pragma unroll 4
    for (int d4 = 0; d4 < DD / 4; ++d4) {
        int4 xv = xrow[d4];                    // x[b, 4*d4 .. 4*d4+3]
        int base = d4 * (4 * CC * MM);
        float g0 = tab[base              + xv.x * MM];
        float g1 = tab[base + 1 * CC*MM  + xv.y * MM];
        float g2 = tab[base + 2 * CC*MM  + xv.z * MM];
        float g3 = tab[base + 3 * CC*MM  + xv.w * MM];
        acc += (g0 + g1) + (g2 + g3);
    }

    float ll = acc + logw[m];

    // logsumexp over the 16-lane m-group
    float mx = ll;
    #pragma unroll
    for (int off = 8; off; off >>= 1)
        mx = fmaxf(mx, __shfl_xor(mx, off, 64));
    float e = __expf(ll - mx);
    #pragma unroll
    for (int off = 8; off; off >>= 1)
        e += __shfl_xor(e, off, 64);

    if (m == 0) out[b] = mx + __logf(e);
}

extern "C" void kernel_launch(void* const* d_in, const int* in_sizes, int n_in,
                              void* d_out, int out_size, void* d_ws, size_t ws_size,
                              hipStream_t stream) {
    const int*   x    = (const int*)d_in[0];     // [B][D]
    const float* mw   = (const float*)d_in[1];   // [M]
    const float* cate = (const float*)d_in[2];   // [M][D][C]
    float* out = (float*)d_out;

    float* logp_t = (float*)d_ws;                         // D*C*M floats = 409600 B
    float* logw   = logp_t + (size_t)DD * CC * MM;        // 16 floats

    // prep: one thread per (m,d) row -> 2048 threads
    prep_kernel<<<(MM * DD + 255) / 256, 256, 0, stream>>>(cate, mw, logp_t, logw);

    // gather: 16 batch rows per 256-thread block
    gather_kernel<<<BB / 16, 256, 0, stream>>>(x, logp_t, logw, out);
}

// Round 2
// 23.349 us; speedup vs baseline: 1.4571x; 1.4571x over previous
//
#include <hip/hip_runtime.h>
#include <hip/hip_bf16.h>

#define MM 16      // mixtures
#define DD 128     // visible dims
#define CC 50      // categories
#define BB 32768   // batch

// ---------------------------------------------------------------------------
// Kernel 1: one WAVE per (m,d) row. Lanes 0..49 load the C=50 logits
// (coalesced 200B), shfl-reduce log_softmax, store bf16 transposed to
// [D][C][M] so the 16 m-values per (d,c) are one contiguous 32B segment.
// 2048 waves -> 8 waves/CU (vs 32 waves TOTAL in the previous version).
// ---------------------------------------------------------------------------
__global__ __launch_bounds__(256) void prep_kernel(
    const float* __restrict__ cate,    // [M][D][C] f32
    const float* __restrict__ mw,      // [M]
    unsigned short* __restrict__ tabw, // [D][C][M] bf16
    float* __restrict__ logw)          // [M]
{
    const int wid  = (blockIdx.x * 256 + threadIdx.x) >> 6;  // 0..2047
    const int lane = threadIdx.x & 63;
    const int m = wid >> 7;        // wid / DD
    const int d = wid & (DD - 1);  // wid % DD

    const float* row = cate + (m * DD + d) * CC;
    float v = (lane < CC) ? row[lane] : -1e30f;

    float mx = v;
    #pragma unroll
    for (int off = 32; off; off >>= 1)
        mx = fmaxf(mx, __shfl_xor(mx, off, 64));
    float e = (lane < CC) ? __expf(v - mx) : 0.f;
    #pragma unroll
    for (int off = 32; off; off >>= 1)
        e += __shfl_xor(e, off, 64);
    float lse = mx + __logf(e);

    if (lane < CC) {
        float lp = v - lse;
        unsigned int bits = __float_as_uint(lp);
        bits += 0x7fffu + ((bits >> 16) & 1u);   // round-to-nearest-even
        tabw[(d * CC + lane) * MM + m] = (unsigned short)(bits >> 16);
    }

    if (wid == 0 && lane < MM) {
        float mw_l = mw[lane];
        float mmx = -1e30f;
        #pragma unroll
        for (int i = 0; i < MM; ++i) mmx = fmaxf(mmx, mw[i]);
        float s = 0.f;
        #pragma unroll
        for (int i = 0; i < MM; ++i) s += __expf(mw[i] - mmx);
        logw[lane] = mw_l - (mmx + __logf(s));
    }
}

// ---------------------------------------------------------------------------
// Kernel 2: 8 lanes per batch row b; lane l owns mixture pair (2l, 2l+1)
// packed as 2 bf16 in one u32. Per d the 8 lanes read one contiguous 32B
// segment tab[d][c][0..15]. Wave = 8 rows; block = 32 rows; grid = 1024.
// Halves wave count and gather-instruction count vs the 16-lane layout.
// ---------------------------------------------------------------------------
__global__ __launch_bounds__(256) void gather_kernel(
    const int* __restrict__ x,            // [B][D] int32
    const unsigned int* __restrict__ tab, // [D][C][8] u32 (= bf16 pairs)
    const float* __restrict__ logw,       // [M]
    float* __restrict__ out)              // [B]
{
    const int tid  = threadIdx.x;
    const int l    = tid & 7;        // mixture-pair index
    const int bsub = tid >> 3;       // 0..31
    const int b    = blockIdx.x * 32 + bsub;

    const int4* __restrict__ xrow = (const int4*)(x + b * DD);
    const unsigned int* __restrict__ t = tab + l;

    float accx = 0.f, accy = 0.f;
    #pragma unroll 8
    for (int d4 = 0; d4 < DD / 4; ++d4) {
        int4 xv = xrow[d4];
        int base = d4 * (4 * CC * 8);
        unsigned int u0 = t[base             + xv.x * 8];
        unsigned int u1 = t[base + 1*CC*8    + xv.y * 8];
        unsigned int u2 = t[base + 2*CC*8    + xv.z * 8];
        unsigned int u3 = t[base + 3*CC*8    + xv.w * 8];
        accx += __uint_as_float(u0 << 16) + __uint_as_float(u1 << 16)
              + __uint_as_float(u2 << 16) + __uint_as_float(u3 << 16);
        accy += __uint_as_float(u0 & 0xffff0000u) + __uint_as_float(u1 & 0xffff0000u)
              + __uint_as_float(u2 & 0xffff0000u) + __uint_as_float(u3 & 0xffff0000u);
    }

    float llx = accx + logw[2 * l];
    float lly = accy + logw[2 * l + 1];

    // logsumexp over 16 mixtures: in-lane pair + 8-lane group reduce
    float mx = fmaxf(llx, lly);
    #pragma unroll
    for (int off = 4; off; off >>= 1)
        mx = fmaxf(mx, __shfl_xor(mx, off, 64));
    float e = __expf(llx - mx) + __expf(lly - mx);
    #pragma unroll
    for (int off = 4; off; off >>= 1)
        e += __shfl_xor(e, off, 64);

    if (l == 0) out[b] = mx + __logf(e);
}

extern "C" void kernel_launch(void* const* d_in, const int* in_sizes, int n_in,
                              void* d_out, int out_size, void* d_ws, size_t ws_size,
                              hipStream_t stream) {
    const int*   x    = (const int*)d_in[0];     // [B][D]
    const float* mw   = (const float*)d_in[1];   // [M]
    const float* cate = (const float*)d_in[2];   // [M][D][C]
    float* out = (float*)d_out;

    unsigned short* tabw = (unsigned short*)d_ws;           // D*C*M bf16 = 204800 B
    float* logw = (float*)((char*)d_ws + (size_t)DD * CC * MM * sizeof(unsigned short));

    // prep: one wave per (m,d) row -> 2048 waves (512 blocks x 4 waves)
    prep_kernel<<<(MM * DD) / 4, 256, 0, stream>>>(cate, mw, tabw, logw);

    // gather: 32 batch rows per 256-thread block
    gather_kernel<<<BB / 32, 256, 0, stream>>>(x, (const unsigned int*)tabw, logw, out);
}